// Round 8
// baseline (982.198 us; speedup 1.0000x reference)
//
#include <hip/hip_runtime.h>
#include <hip/hip_bf16.h>

// LagLlama forward. fp32/bf16 input autodetect -> bf16 copies in ws.
// fp32 residual stream. Round 13 = R12 + division-free cvt (flattened
// descriptors + binary search) + silu fused into w12 GEMM epilogue via
// row-interleaved w1|w2 and lane-pair shfl (silu_mul_k deleted).
// B=2 T=1024 C=1024 NH=16 DH=64 L=4 HFF=2816

#define B_   2
#define T_   1024
#define C_   1024
#define NH_  16
#define DH_  64
#define L_   4
#define HFF_ 2816
#define EPS_ 1e-5f

typedef unsigned short u16;
typedef short bf16x8 __attribute__((ext_vector_type(8)));
typedef unsigned short u16x8 __attribute__((ext_vector_type(8)));
typedef float f32x4 __attribute__((ext_vector_type(4)));

__device__ __forceinline__ float b2f(u16 u) {
    union { unsigned int i; float f; } v; v.i = ((unsigned int)u) << 16; return v.f;
}
__device__ __forceinline__ u16 f2b(float f) {
    union { unsigned int i; float f; } v; v.f = f;
    unsigned int r = (v.i + 0x7fff + ((v.i >> 16) & 1)) >> 16;
    return (u16)r;
}

// flag: 0 = inputs are bf16, 1 = inputs are fp32 (detected from x's raw bits)
__global__ void detect_k(const unsigned int* __restrict__ xw, int* __restrict__ flag)
{
    int tid = threadIdx.x;
    int cnt = 0;
#pragma unroll
    for (int i = 0; i < 4; ++i) {
        unsigned int w = xw[tid * 4 + i];
        unsigned int e = (w >> 7) & 0xFF;
        if (e >= 0x70 && e <= 0x87) cnt++;
    }
#pragma unroll
    for (int off = 32; off; off >>= 1) cnt += __shfl_down(cnt, off);
    if (tid == 0) flag[0] = (cnt > 128) ? 0 : 1;
}

// ---------------------------------------------------------------------------
// Fused relayout+convert, division-free. Each descriptor is a linear vec4
// range of ONE (tensor, layer-chunk): src4[srcOff + loc] -> dst4[map(loc)].
// mode 0: dj = loc. mode 1/2: w1/w2 row-interleave into cw12 — source rows
// are 256 vec4 (C=1024), dst row 2n(+1): dj = ((loc>>8)<<9) + (loc&255) [+256].
// Descriptor found by 5-step binary search on prefix sums (no 64-bit div).
// ---------------------------------------------------------------------------
struct CvtD { const void* src; u16* dst; long srcOff; int mode; int _pad; };
struct CvtPack { CvtD d[32]; long start[33]; int nd; };

__global__ void cvt_all_k(CvtPack p, const int* __restrict__ flag)
{
    const int f = flag[0];
    const long total = p.start[p.nd];
    long i = (long)blockIdx.x * 256 + threadIdx.x;
    const long stride = (long)gridDim.x * 256;
    for (; i < total; i += stride) {
        int lo = 0, hi = p.nd - 1;
#pragma unroll 5
        for (int it = 0; it < 5; ++it) {
            int mid = (lo + hi + 1) >> 1;
            if (p.start[mid] <= i) lo = mid; else hi = mid - 1;
        }
        const int ti = lo;
        const long loc = i - p.start[ti];
        const int mode = p.d[ti].mode;
        long dj = (mode == 0) ? loc
                : ((loc >> 8) << 9) + (loc & 255) + ((mode == 2) ? 256 : 0);
        ushort4 o;
        if (f) {
            float4 v = ((const float4*)p.d[ti].src)[p.d[ti].srcOff + loc];
            o.x = f2b(v.x); o.y = f2b(v.y); o.z = f2b(v.z); o.w = f2b(v.w);
        } else {
            o = ((const ushort4*)p.d[ti].src)[p.d[ti].srcOff + loc];
        }
        ((ushort4*)p.d[ti].dst)[dj] = o;
    }
}

// ---------------------------------------------------------------------------
// GEMM: C[m,n] = sum_k A[m,k] * B[n,k]   (A: MxK lda, B: NxK ldb)
// MODE 0: write bf16 to Cb.
//   ropeMode: RoPE in epilogue for cols < 2048 (q|k of fused qkv) via rt.
//   siluMode: B is row-interleaved [w1|w2]; out col 2m = u1[m] (even lanes),
//     col 2m+1 = u2[m] (odd lanes). Epilogue: silu(u1)*u2 via __shfl_xor(1),
//     even lanes store compact col m to Cb (ldc = HFF).
// MODE 1: z = K-slice; slices 0..kSplit-2 -> fp32 partials Pf[z*M*ldc + off];
//   slice kSplit-1 does non-atomic Cf[off] += acc (single writer per cell).
// Bijective XCD swizzle (m204). 1-deep prefetch double-buffer: stage(j+1)
// issued before compute(j); single barrier per K-step.
// ---------------------------------------------------------------------------
template<int MODE>
__global__ __launch_bounds__(256, 2)
void gemm_bt(const u16* __restrict__ A, const u16* __restrict__ Bm,
             u16* __restrict__ Cb, float* __restrict__ Cf,
             float* __restrict__ Pf,
             int M, int N, int K, int lda, int ldb, int ldc,
             int kSplit, int ropeMode, int siluMode,
             const float2* __restrict__ rt)
{
    __shared__ __align__(16) u16 tA[2][128 * 32];
    __shared__ __align__(16) u16 tB[2][128 * 32];

    // --- XCD-aware bijective remap of the linear workgroup id ---
    const unsigned nx = gridDim.x, ny = gridDim.y;
    const unsigned nwg = nx * ny * gridDim.z;
    const unsigned lin = blockIdx.x + nx * (blockIdx.y + ny * blockIdx.z);
    const unsigned qd = nwg >> 3, rm = nwg & 7;
    const unsigned xcd = lin & 7, pos = lin >> 3;
    const unsigned wg = (xcd < rm ? xcd * (qd + 1)
                                  : rm * (qd + 1) + (xcd - rm) * qd) + pos;
    const unsigned bx = wg % nx;
    const unsigned tmp = wg / nx;
    const unsigned by = tmp % ny;
    const unsigned bz = tmp / ny;

    const int z = (int)bz;
    int kBeg = 0, kEnd = K;
    if (MODE == 1) {
        int ks = K / kSplit;
        kBeg = z * ks; kEnd = kBeg + ks;
    }

    const int row0 = by * 128;
    const int col0 = bx * 128;

    const int tid  = threadIdx.x;
    const int lane = tid & 63;
    const int wave = tid >> 6;
    const int wr = wave >> 1, wc = wave & 1;   // 2x2 waves of 64x64
    const int lrow = lane & 15;
    const int kg   = lane >> 4;

    f32x4 acc[4][4] = {};

    auto stage = [&](int bb, int k0) {
#pragma unroll
        for (int i = 0; i < 2; ++i) {          // A tile: 512 x 16B chunks
            int chunk = i * 256 + tid;
            int r = chunk >> 2, cg = chunk & 3;
            const u16* ga = A + (long)(row0 + r) * lda + (k0 + cg * 8);
            u16* la = tA[bb] + (size_t)(i * 256 + wave * 64) * 8;  // wave-uniform
            __builtin_amdgcn_global_load_lds(
                (const __attribute__((address_space(1))) void*)ga,
                (__attribute__((address_space(3))) void*)la, 16, 0, 0);
        }
#pragma unroll
        for (int i = 0; i < 2; ++i) {          // B tile
            int chunk = i * 256 + tid;
            int r = chunk >> 2, cg = chunk & 3;
            const u16* gb = Bm + (long)(col0 + r) * ldb + (k0 + cg * 8);
            u16* lb = tB[bb] + (size_t)(i * 256 + wave * 64) * 8;
            __builtin_amdgcn_global_load_lds(
                (const __attribute__((address_space(1))) void*)gb,
                (__attribute__((address_space(3))) void*)lb, 16, 0, 0);
        }
    };

    stage(0, kBeg);
    int cur = 0;

    for (int k0 = kBeg; k0 < kEnd; k0 += 32) {
        __syncthreads();                 // buf[cur] staged (vmcnt drained);
                                         // prior reads of buf[cur^1] done
        if (k0 + 32 < kEnd) stage(cur ^ 1, k0 + 32);   // prefetch overlaps

        const u16* pA_ = tA[cur];
        const u16* pB_ = tB[cur];
        bf16x8 af[4], bfr[4];
#pragma unroll
        for (int ti = 0; ti < 4; ++ti)
            af[ti] = *(const bf16x8*)&pA_[(wr * 64 + ti * 16 + lrow) * 32 + kg * 8];
#pragma unroll
        for (int tj = 0; tj < 4; ++tj)
            bfr[tj] = *(const bf16x8*)&pB_[(wc * 64 + tj * 16 + lrow) * 32 + kg * 8];
#pragma unroll
        for (int ti = 0; ti < 4; ++ti)
#pragma unroll
            for (int tj = 0; tj < 4; ++tj)
                acc[ti][tj] = __builtin_amdgcn_mfma_f32_16x16x32_bf16(
                    af[ti], bfr[tj], acc[ti][tj], 0, 0, 0);
        cur ^= 1;
    }

    // Epilogue: D[row = kg*4 + r][col = lane&15] per 16x16 tile.
    const int rbase = row0 + wr * 64;
    const int cbase = col0 + wc * 64 + lrow;

    if (MODE == 0) {
        if (siluMode) {
            const bool even = ((lrow & 1) == 0);
            const int ccb = ((col0 + wc * 64) >> 1) + (lrow >> 1);
#pragma unroll
            for (int ti = 0; ti < 4; ++ti) {
#pragma unroll
                for (int r = 0; r < 4; ++r) {
                    int row = rbase + ti * 16 + kg * 4 + r;
#pragma unroll
                    for (int tj = 0; tj < 4; ++tj) {
                        float v = acc[ti][tj][r];
                        float pv = __shfl_xor(v, 1);
                        if (even) {
                            float res = (v / (1.f + __expf(-v))) * pv;
                            Cb[(long)row * ldc + ccb + tj * 8] = f2b(res);
                        }
                    }
                }
            }
        } else {
            const bool doRope = ropeMode && (cbase < 2048);  // q|k cols of qkv
#pragma unroll
            for (int ti = 0; ti < 4; ++ti) {
#pragma unroll
                for (int r = 0; r < 4; ++r) {
                    int row = rbase + ti * 16 + kg * 4 + r;
                    float o0 = acc[ti][0][r], o1 = acc[ti][1][r];
                    float o2 = acc[ti][2][r], o3 = acc[ti][3][r];
                    if (doRope) {
                        int t = row & 1023;
                        float2 c0 = rt[t * 32 + lrow];         // i = lrow
                        float2 c1 = rt[t * 32 + 16 + lrow];    // i = 16 + lrow
                        float n0 = o0 * c0.x - o2 * c0.y;
                        float n2 = o2 * c0.x + o0 * c0.y;
                        float n1 = o1 * c1.x - o3 * c1.y;
                        float n3 = o3 * c1.x + o1 * c1.y;
                        o0 = n0; o1 = n1; o2 = n2; o3 = n3;
                    }
                    float ov[4] = { o0, o1, o2, o3 };
#pragma unroll
                    for (int tj = 0; tj < 4; ++tj)
                        Cb[(long)row * ldc + cbase + tj * 16] = f2b(ov[tj]);
                }
            }
        }
    } else {
        const size_t pstr = (size_t)M * ldc;
        const bool last = (z == kSplit - 1);
#pragma unroll
        for (int ti = 0; ti < 4; ++ti) {
#pragma unroll
            for (int r = 0; r < 4; ++r) {
                int row = rbase + ti * 16 + kg * 4 + r;
#pragma unroll
                for (int tj = 0; tj < 4; ++tj) {
                    long off = (long)row * ldc + cbase + tj * 16;
                    if (last) Cf[off] += acc[ti][tj][r];   // single writer/cell
                    else      Pf[(size_t)z * pstr + off] = acc[ti][tj][r];
                }
            }
        }
    }
}

// ---------------------------------------------------------------------------
// Fused causal flash attention. One block = (b, head, 64 q-rows), 4 waves x
// 16 q-rows. K/V tiles double-buffered in LDS via global_load_lds with
// pre-swizzled global source; prefetch of tile j+1 overlaps compute of j.
// Longest q-tiles are dispatched first (qt = 15 - pos) to trim the tail.
// ---------------------------------------------------------------------------
__global__ __launch_bounds__(256, 2)
void flash_k(const u16* __restrict__ qkv, const u16* __restrict__ vt,
             u16* __restrict__ y)
{
    __shared__ __align__(16) u16 tK[2][64 * 64];
    __shared__ __align__(16) u16 tV[2][64 * 64];
    __shared__ __align__(16) u16 tP[4][16 * 64];

    const int bid0 = blockIdx.x;
    const int bid  = (bid0 & 7) * 64 + (bid0 >> 3);   // XCD swizzle (512%8==0)
    const int qt = 15 - (bid & 15);                   // longest first
    const int hh = (bid >> 4) & 15;
    const int b  = bid >> 8;

    const int tid  = threadIdx.x;
    const int lane = tid & 63;
    const int w    = tid >> 6;           // wave 0..3
    const int l15  = lane & 15;
    const int kg   = lane >> 4;          // 0..3

    const int wq0 = qt * 64 + w * 16;    // wave's first q row
    u16* tPw = tP[w];

    bf16x8 qf[2];
#pragma unroll
    for (int dk = 0; dk < 2; ++dk)
        qf[dk] = *(const bf16x8*)(qkv
            + (size_t)(b * 1024 + wq0 + l15) * 3072 + hh * 64 + dk * 32 + kg * 8);

    f32x4 acc_o[4] = {};
    float mrun = -3e38f;
    float lrun = 0.f;

    const u16* Kg0 = qkv + (size_t)(b * 1024) * 3072 + 1024 + hh * 64;
    const u16* Vg0 = vt + (size_t)((b * 16 + hh) * 64) * 1024;

    auto stage = [&](int bb, int j) {
#pragma unroll
        for (int i = 0; i < 2; ++i) {
            int chunk = i * 256 + tid;   // granule id 0..511
            int row = chunk >> 3, gc = chunk & 7;
            int sgc = gc ^ (row & 7);
            const u16* ga = Kg0 + (size_t)(j * 64 + row) * 3072 + sgc * 8;
            u16* la = tK[bb] + (size_t)(i * 256 + w * 64) * 8;  // wave-uniform
            __builtin_amdgcn_global_load_lds(
                (const __attribute__((address_space(1))) void*)ga,
                (__attribute__((address_space(3))) void*)la, 16, 0, 0);
            const u16* gb = Vg0 + (size_t)row * 1024 + j * 64 + sgc * 8;
            u16* lb = tV[bb] + (size_t)(i * 256 + w * 64) * 8;
            __builtin_amdgcn_global_load_lds(
                (const __attribute__((address_space(1))) void*)gb,
                (__attribute__((address_space(3))) void*)lb, 16, 0, 0);
        }
    };

    stage(0, 0);
    int cur = 0;

    for (int j = 0; j <= qt; ++j) {
        __syncthreads();
        if (j < qt) stage(cur ^ 1, j + 1);   // prefetch overlaps compute

        const u16* K_ = tK[cur];
        const u16* V_ = tV[cur];

        f32x4 s[4] = {};
#pragma unroll
        for (int dk = 0; dk < 2; ++dk) {
            bf16x8 ak[4];
#pragma unroll
            for (int kvt = 0; kvt < 4; ++kvt) {
                int row = kvt * 16 + l15;
                int g = (dk * 4 + kg) ^ (row & 7);
                ak[kvt] = *(const bf16x8*)&K_[row * 64 + g * 8];
            }
#pragma unroll
            for (int kvt = 0; kvt < 4; ++kvt)
                s[kvt] = __builtin_amdgcn_mfma_f32_16x16x32_bf16(
                    ak[kvt], qf[dk], s[kvt], 0, 0, 0);
        }

        float tmax = -3e38f;
        const bool maskt = (j == qt);
#pragma unroll
        for (int kvt = 0; kvt < 4; ++kvt) {
            f32x4 v = s[kvt];
#pragma unroll
            for (int r = 0; r < 4; ++r) {
                float sv = v[r] * 0.125f;
                if (maskt && (j * 64 + kvt * 16 + kg * 4 + r > wq0 + l15))
                    sv = -3e38f;
                v[r] = sv;
                tmax = fmaxf(tmax, sv);
            }
            s[kvt] = v;
        }
        tmax = fmaxf(tmax, __shfl_xor(tmax, 16));
        tmax = fmaxf(tmax, __shfl_xor(tmax, 32));

        const float mn = fmaxf(mrun, tmax);
        const float sf = __expf(mrun - mn);
        mrun = mn;

#pragma unroll
        for (int ro = 0; ro < 4; ++ro) {
            float f = __shfl(sf, kg * 4 + ro);
#pragma unroll
            for (int dj = 0; dj < 4; ++dj)
                acc_o[dj][ro] *= f;
        }

        float tsum = 0.f;
#pragma unroll
        for (int kvt = 0; kvt < 4; ++kvt) {
            f32x4 v = s[kvt];
            float p0 = __expf(v[0] - mn);
            float p1 = __expf(v[1] - mn);
            float p2 = __expf(v[2] - mn);
            float p3 = __expf(v[3] - mn);
            tsum += p0 + p1 + p2 + p3;
            ushort4 pk;
            pk.x = f2b(p0); pk.y = f2b(p1); pk.z = f2b(p2); pk.w = f2b(p3);
            int g = (kvt * 2 + (kg >> 1)) ^ (l15 & 7);
            *(ushort4*)&tPw[l15 * 64 + g * 8 + (kg & 1) * 4] = pk;
        }
        tsum += __shfl_xor(tsum, 16);
        tsum += __shfl_xor(tsum, 32);
        lrun = lrun * sf + tsum;

#pragma unroll
        for (int ki = 0; ki < 2; ++ki) {
            bf16x8 ap, bv[4];
            {
                int g = (ki * 4 + kg) ^ (l15 & 7);
                ap = *(const bf16x8*)&tPw[l15 * 64 + g * 8];
            }
#pragma unroll
            for (int dj = 0; dj < 4; ++dj) {
                int row = dj * 16 + l15;
                int g = (ki * 4 + kg) ^ (row & 7);
                bv[dj] = *(const bf16x8*)&V_[row * 64 + g * 8];
            }
#pragma unroll
            for (int dj = 0; dj < 4; ++dj)
                acc_o[dj] = __builtin_amdgcn_mfma_f32_16x16x32_bf16(
                    ap, bv[dj], acc_o[dj], 0, 0, 0);
        }
        cur ^= 1;
    }

    const float inv = 1.0f / lrun;
#pragma unroll
    for (int ro = 0; ro < 4; ++ro) {
        float iv = __shfl(inv, kg * 4 + ro);
        size_t rowo = (size_t)(b * 1024 + wq0 + kg * 4 + ro) * 1024
                    + hh * 64 + l15;
#pragma unroll
        for (int dj = 0; dj < 4; ++dj)
            y[rowo + dj * 16] = f2b(acc_o[dj][ro] * iv);
    }
}

// h[bt,c] = sum_f x[bt,f] * w_in[c,f]   (K=9, fp32 out)
__global__ void input_proj_k(const u16* __restrict__ x, const u16* __restrict__ w,
                             float* __restrict__ h)
{
    int idx = blockIdx.x * 256 + threadIdx.x;      // 2M
    int bt = idx >> 10, c = idx & 1023;
    float s = 0.f;
#pragma unroll
    for (int f = 0; f < 9; ++f) s += b2f(x[bt * 9 + f]) * b2f(w[c * 9 + f]);
    h[idx] = s;
}

// Fused residual-reduce + RMSNorm.
// v = h[row] + sum_{p<nP} P[p][row];  if (hOut) hOut[row] = v;
// out[row] = v * rsqrt(mean(v^2)+eps) * g.   isFinal&&flag -> fp32 out.
__global__ void rms_k(const float* __restrict__ h, const float* __restrict__ P,
                      int nP, const u16* __restrict__ g,
                      void* __restrict__ out, float* __restrict__ hOut,
                      int isFinal, const int* __restrict__ flag)
{
    __shared__ float red[8];
    const int row = blockIdx.x;
    const int tid = threadIdx.x;
    float4 v = ((const float4*)(h + (size_t)row * C_))[tid];
    for (int p = 0; p < nP; ++p) {
        float4 pv = ((const float4*)P)[(size_t)p * 524288 + row * 256 + tid];
        v.x += pv.x; v.y += pv.y; v.z += pv.z; v.w += pv.w;
    }
    if (hOut) ((float4*)hOut)[(size_t)row * 256 + tid] = v;
    float ss = v.x * v.x + v.y * v.y + v.z * v.z + v.w * v.w;
#pragma unroll
    for (int off = 32; off; off >>= 1) ss += __shfl_down(ss, off);
    int lane = tid & 63, wave = tid >> 6;
    if (lane == 0) red[wave] = ss;
    __syncthreads();
    if (tid == 0)
        red[4] = rsqrtf((red[0] + red[1] + red[2] + red[3]) / (float)C_ + EPS_);
    __syncthreads();
    const float r = red[4];
    ushort4 gv = ((const ushort4*)g)[tid];
    float o0 = v.x * r * b2f(gv.x);
    float o1 = v.y * r * b2f(gv.y);
    float o2 = v.z * r * b2f(gv.z);
    float o3 = v.w * r * b2f(gv.w);
    if (isFinal && flag[0]) {
        ((float4*)out)[(size_t)row * 256 + tid] = make_float4(o0, o1, o2, o3);
    } else {
        ushort4 o; o.x = f2b(o0); o.y = f2b(o1); o.z = f2b(o2); o.w = f2b(o3);
        ((ushort4*)out)[(size_t)row * 256 + tid] = o;
    }
}

// cos/sin table: tab[t*32+i] = {cos,sin}(t * 10000^(-i/32)), t<1024, i<32
__global__ void rope_tab_k(float2* __restrict__ tab)
{
    int idx = blockIdx.x * 256 + threadIdx.x;      // 32768
    int i = idx & 31;
    int t = idx >> 5;
    float invf = powf(10000.0f, -(float)i / 32.0f);
    float fr = (float)t * invf;
    tab[idx] = make_float2(cosf(fr), sinf(fr));
}

// vt[b,h,d,s] = qkv[b,s, 2048 + h*64 + d]  — LDS-tiled 64x64 transpose.
__global__ void vtrans_k(const u16* __restrict__ qkv, u16* __restrict__ vt)
{
    __shared__ u16 tile[64][68];                   // pad 4 u16
    const int bz = blockIdx.x;                     // 512 = 2b * 16h * 16s-tiles
    const int s0 = (bz & 15) << 6;
    const int hh = (bz >> 4) & 15;
    const int b  = bz >> 8;
    const int tid = threadIdx.x;
#pragma unroll
    for (int it = 0; it < 2; ++it) {
        int id = it * 256 + tid;                   // 0..511
        int r  = id >> 3;                          // s-row within tile
        int cg = id & 7;                           // 8-wide d chunk
        const u16* src = qkv + (size_t)(b * 1024 + s0 + r) * 3072
                             + 2048 + hh * 64 + cg * 8;
        ushort4 a0 = *(const ushort4*)src;
        ushort4 a1 = *(const ushort4*)(src + 4);
        *(ushort4*)&tile[r][cg * 8]     = a0;
        *(ushort4*)&tile[r][cg * 8 + 4] = a1;
    }
    __syncthreads();
#pragma unroll
    for (int it = 0; it < 2; ++it) {
        int id = it * 256 + tid;
        int d  = id >> 3;                          // d row of output
        int cg = id & 7;                           // 8-wide s chunk
        ushort4 o0, o1;
        o0.x = tile[cg * 8 + 0][d]; o0.y = tile[cg * 8 + 1][d];
        o0.z = tile[cg * 8 + 2][d]; o0.w = tile[cg * 8 + 3][d];
        o1.x = tile[cg * 8 + 4][d]; o1.y = tile[cg * 8 + 5][d];
        o1.z = tile[cg * 8 + 6][d]; o1.w = tile[cg * 8 + 7][d];
        u16* dst = vt + (size_t)((b * 16 + hh) * 64 + d) * 1024 + s0 + cg * 8;
        *(ushort4*)dst       = o0;
        *(ushort4*)(dst + 4) = o1;
    }
}

// ---------------------------------------------------------------------------
static inline void launch_gemm(bool add, const u16* A, const u16* Bm, void* C,
                               float* Pf,
                               int M, int N, int K, int lda, int ldb, int ldc,
                               int kSplit, int ropeMode, int siluMode,
                               const float2* rt, hipStream_t stream)
{
    dim3 g(N / 128, M / 128, add ? kSplit : 1);
    if (add)
        gemm_bt<1><<<g, 256, 0, stream>>>(A, Bm, nullptr, (float*)C, Pf,
            M, N, K, lda, ldb, ldc, kSplit, 0, 0, nullptr);
    else
        gemm_bt<0><<<g, 256, 0, stream>>>(A, Bm, (u16*)C, nullptr, nullptr,
            M, N, K, lda, ldb, ldc, 1, ropeMode, siluMode, rt);
}

extern "C" void kernel_launch(void* const* d_in, const int* in_sizes, int n_in,
                              void* d_out, int out_size, void* d_ws, size_t ws_size,
                              hipStream_t stream)
{
    char* w = (char*)d_ws;
    // Layout:
    //   [0,8)    h fp32 residual
    //   [8,32)   P: 3 fp32 split-K partial slices (8 MB each); overlaps
    //            qkv [12,24) and vt [24,28) (disjoint lifetimes)
    //   [32,44)  u1c MLP compact buffer [2048][2816] bf16 (11.5 MB)
    //   [56,60)  y attention output
    //   [60,64)  a (rms output, bf16)
    float* h   = (float*)w;
    float* P   = (float*)(w + (8u  << 20));
    u16* qkv   = (u16*)(w + (12u << 20));
    u16* vt    = (u16*)(w + (24u << 20));
    u16* u1c   = (u16*)(w + (32u << 20));
    u16* y     = (u16*)(w + (56u << 20));
    u16* a     = (u16*)(w + (60u << 20));

    size_t off = (size_t)64 << 20;
    u16* cx    = (u16*)(w + off); off += ((size_t)B_*T_*9*2   + 255) & ~(size_t)255;
    u16* cwin  = (u16*)(w + off); off += ((size_t)C_*9*2      + 255) & ~(size_t)255;
    u16* cwqkv = (u16*)(w + off); off += (size_t)L_*3072*1024*2;   // fused q|k|v
    u16* cwo   = (u16*)(w + off); off += (size_t)L_*C_*C_*2;
    u16* cw12  = (u16*)(w + off); off += (size_t)L_*2*HFF_*C_*2;   // interleaved
    u16* cw3   = (u16*)(w + off); off += (size_t)L_*C_*HFF_*2;
    u16* cg1   = (u16*)(w + off); off += ((size_t)L_*C_*2 + 255) & ~(size_t)255;
    u16* cg2   = (u16*)(w + off); off += ((size_t)L_*C_*2 + 255) & ~(size_t)255;
    u16* cgf   = (u16*)(w + off); off += ((size_t)C_*2    + 255) & ~(size_t)255;
    int* flag  = (int*)(w + off); off += 256;
    float2* rtab = (float2*)(w + off);               // 1024*32*8 = 256 KB

    detect_k<<<1, 64, 0, stream>>>((const unsigned int*)d_in[0], flag);

    // --- fused weight conversion: flattened per-(tensor,chunk) descriptors ---
    const long CCv  = (long)C_ * C_ / 4;        // 262144
    const long HCv  = (long)HFF_ * C_ / 4;      // 720896
    CvtPack cp;
    int nd = 0; long cum = 0;
    auto add = [&](const void* s, u16* d, long srcOff, long n, int mode) {
        cp.d[nd] = { s, d, srcOff, mode, 0 };
        cp.start[nd] = cum; cum += n; ++nd;
    };
    add(d_in[0], cx,   0, (long)B_*T_*9/4, 0);
    add(d_in[1], cwin, 0, (long)C_*9/4,    0);
    for (int l = 0; l < L_; ++l)   // wq -> cwqkv cols 0..1023 rows block
        add(d_in[2], cwqkv + (size_t)l*3*CCv*4,           (long)l*CCv,   CCv,   0);
    for (int l = 0; l < L_; ++l)   // wkv
        add(d_in[3], cwqkv + (size_t)(l*3*CCv + CCv)*4,   (long)l*2*CCv, 2*CCv, 0);
    for (int l = 0; l < L_; ++l)   // wo
        add(d_in[4], cwo + (size_t)l*CCv*4,               (long)l*CCv,   CCv,   0);
    for (int l = 0; l < L_; ++l)   // w1 -> even rows of interleaved cw12
        add(d_in[5], cw12 + (size_t)l*2*HCv*4,            (long)l*HCv,   HCv,   1);
    for (int l = 0; l < L_; ++l)   // w2 -> odd rows
        add(d_in[6], cw12 + (size_t)l*2*HCv*4,            (long)l*HCv,   HCv,   2);
    for (int l = 0; l < L_; ++l)   // w3
        add(d_in[7], cw3 + (size_t)l*HCv*4,               (long)l*HCv,   HCv,   0);
    add(d_in[8],  cg1, 0, (long)L_*C_/4, 0);
    add(d_in[9],  cg2, 0, (long)L_*C_/4, 0);
    add(d_in[10], cgf, 0, (long)C_/4,    0);
    cp.start[nd] = cum;
    cp.nd = nd;                                     // 29
    for (int i = nd; i < 32; ++i) { cp.d[i] = { nullptr, nullptr, 0, 0, 0 }; }
    for (int i = nd + 1; i <= 32; ++i) cp.start[i] = cum;
    cvt_all_k<<<4096, 256, 0, stream>>>(cp, flag);

    rope_tab_k<<<128, 256, 0, stream>>>(rtab);

    input_proj_k<<<8192, 256, 0, stream>>>(cx, cwin, h);

    for (int l = 0; l < L_; ++l) {
        const u16* wqkv_l = cwqkv + (size_t)l * 3072 * 1024;
        const u16* wo_l   = cwo   + (size_t)l * C_ * C_;
        const u16* w12_l  = cw12  + (size_t)l * 2 * HFF_ * C_;
        const u16* w3_l   = cw3   + (size_t)l * C_ * HFF_;

        // --- attention ---
        if (l == 0)
            rms_k<<<2048, 256, 0, stream>>>(h, nullptr, 0, cg1, a, nullptr, 0, flag);
        else
            rms_k<<<2048, 256, 0, stream>>>(h, P, 3, cg1 + l * C_, a, h, 0, flag);
        // qkv[2048][3072] = a @ [wq|wk|wv]^T  (single N=3072 GEMM; RoPE fused)
        launch_gemm(false, a, wqkv_l, qkv, nullptr,
                    2048, 3072, 1024, 1024, 1024, 3072, 1, 1, 0, rtab, stream);
        vtrans_k<<<512, 256, 0, stream>>>(qkv, vt);
        flash_k<<<512, 256, 0, stream>>>(qkv, vt, y);
        // wo split-K x4: slices 0-2 -> P, slice 3 RMW h += acc
        launch_gemm(true, y, wo_l, h, P, 2048, 1024, 1024, 1024, 1024, 1024,
                    4, 0, 0, nullptr, stream);

        // --- MLP ---
        rms_k<<<2048, 256, 0, stream>>>(h, P, 3, cg2 + l * C_, a, h, 0, flag);
        // u1c[2048][2816] = silu(a@w1^T) * (a@w2^T) — interleaved B + fused silu
        launch_gemm(false, a, w12_l, u1c, nullptr,
                    2048, 5632, 1024, 1024, 1024, 2816, 1, 0, 1, nullptr, stream);
        // w3 split-K x4 (K=2816 -> 704/slice): slices 0-2 -> P, slice 3 RMW h
        launch_gemm(true, u1c, w3_l, h, P, 2048, 1024, 2816, 2816, 2816, 1024,
                    4, 0, 0, nullptr, stream);
    }

    rms_k<<<2048, 256, 0, stream>>>(h, P, 3, cgf, d_out, nullptr, 1, flag);
}

// Round 9
// 935.944 us; speedup vs baseline: 1.0494x; 1.0494x over previous
//
#include <hip/hip_runtime.h>
#include <hip/hip_bf16.h>

// LagLlama forward. fp32/bf16 input autodetect -> bf16 copies in ws.
// fp32 residual stream. Round 14 = R13 with cvt fixed: descriptor chosen by
// blockIdx.y (wave-uniform scalar kernarg access, no search/div/scratch).
// silu stays fused in w12 GEMM epilogue (interleaved w1|w2).
// B=2 T=1024 C=1024 NH=16 DH=64 L=4 HFF=2816

#define B_   2
#define T_   1024
#define C_   1024
#define NH_  16
#define DH_  64
#define L_   4
#define HFF_ 2816
#define EPS_ 1e-5f

typedef unsigned short u16;
typedef short bf16x8 __attribute__((ext_vector_type(8)));
typedef unsigned short u16x8 __attribute__((ext_vector_type(8)));
typedef float f32x4 __attribute__((ext_vector_type(4)));

__device__ __forceinline__ float b2f(u16 u) {
    union { unsigned int i; float f; } v; v.i = ((unsigned int)u) << 16; return v.f;
}
__device__ __forceinline__ u16 f2b(float f) {
    union { unsigned int i; float f; } v; v.f = f;
    unsigned int r = (v.i + 0x7fff + ((v.i >> 16) & 1)) >> 16;
    return (u16)r;
}

// flag: 0 = inputs are bf16, 1 = inputs are fp32 (detected from x's raw bits)
__global__ void detect_k(const unsigned int* __restrict__ xw, int* __restrict__ flag)
{
    int tid = threadIdx.x;
    int cnt = 0;
#pragma unroll
    for (int i = 0; i < 4; ++i) {
        unsigned int w = xw[tid * 4 + i];
        unsigned int e = (w >> 7) & 0xFF;
        if (e >= 0x70 && e <= 0x87) cnt++;
    }
#pragma unroll
    for (int off = 32; off; off >>= 1) cnt += __shfl_down(cnt, off);
    if (tid == 0) flag[0] = (cnt > 128) ? 0 : 1;
}

// ---------------------------------------------------------------------------
// Fused relayout+convert. One descriptor per (tensor, layer-chunk), selected
// by blockIdx.y (UNIFORM -> scalar kernarg loads, no scratch). Each block
// grid-strides over its descriptor's vec4 range:
//   src4[srcOff + i] -> dst4[map(i)]
// mode 0: dj = i. mode 1/2: w1/w2 row-interleave (src row = 256 vec4):
//   dj = ((i>>8)<<9) + (i&255) [+256 for mode 2].
// ---------------------------------------------------------------------------
struct CvtD { const void* src; u16* dst; long srcOff; long n; int mode; int pad; };
struct CvtPack { CvtD d[29]; };

__global__ void cvt_all_k(CvtPack p, const int* __restrict__ flag)
{
    const int f = flag[0];
    const CvtD d = p.d[blockIdx.y];          // uniform per block
    long i = (long)blockIdx.x * 256 + threadIdx.x;
    const long stride = (long)gridDim.x * 256;
    for (; i < d.n; i += stride) {
        long dj = (d.mode == 0) ? i
                : ((i >> 8) << 9) + (i & 255) + ((d.mode == 2) ? 256 : 0);
        ushort4 o;
        if (f) {
            float4 v = ((const float4*)d.src)[d.srcOff + i];
            o.x = f2b(v.x); o.y = f2b(v.y); o.z = f2b(v.z); o.w = f2b(v.w);
        } else {
            o = ((const ushort4*)d.src)[d.srcOff + i];
        }
        ((ushort4*)d.dst)[dj] = o;
    }
}

// ---------------------------------------------------------------------------
// GEMM: C[m,n] = sum_k A[m,k] * B[n,k]   (A: MxK lda, B: NxK ldb)
// MODE 0: write bf16 to Cb.
//   ropeMode: RoPE in epilogue for cols < 2048 (q|k of fused qkv) via rt.
//   siluMode: B is row-interleaved [w1|w2]; out col 2m = u1[m] (even lanes),
//     col 2m+1 = u2[m] (odd lanes). Epilogue: silu(u1)*u2 via __shfl_xor(1),
//     even lanes store compact col m to Cb (ldc = HFF).
// MODE 1: z = K-slice; slices 0..kSplit-2 -> fp32 partials Pf[z*M*ldc + off];
//   slice kSplit-1 does non-atomic Cf[off] += acc (single writer per cell).
// Bijective XCD swizzle (m204). 1-deep prefetch double-buffer: stage(j+1)
// issued before compute(j); single barrier per K-step.
// ---------------------------------------------------------------------------
template<int MODE>
__global__ __launch_bounds__(256, 2)
void gemm_bt(const u16* __restrict__ A, const u16* __restrict__ Bm,
             u16* __restrict__ Cb, float* __restrict__ Cf,
             float* __restrict__ Pf,
             int M, int N, int K, int lda, int ldb, int ldc,
             int kSplit, int ropeMode, int siluMode,
             const float2* __restrict__ rt)
{
    __shared__ __align__(16) u16 tA[2][128 * 32];
    __shared__ __align__(16) u16 tB[2][128 * 32];

    // --- XCD-aware bijective remap of the linear workgroup id ---
    const unsigned nx = gridDim.x, ny = gridDim.y;
    const unsigned nwg = nx * ny * gridDim.z;
    const unsigned lin = blockIdx.x + nx * (blockIdx.y + ny * blockIdx.z);
    const unsigned qd = nwg >> 3, rm = nwg & 7;
    const unsigned xcd = lin & 7, pos = lin >> 3;
    const unsigned wg = (xcd < rm ? xcd * (qd + 1)
                                  : rm * (qd + 1) + (xcd - rm) * qd) + pos;
    const unsigned bx = wg % nx;
    const unsigned tmp = wg / nx;
    const unsigned by = tmp % ny;
    const unsigned bz = tmp / ny;

    const int z = (int)bz;
    int kBeg = 0, kEnd = K;
    if (MODE == 1) {
        int ks = K / kSplit;
        kBeg = z * ks; kEnd = kBeg + ks;
    }

    const int row0 = by * 128;
    const int col0 = bx * 128;

    const int tid  = threadIdx.x;
    const int lane = tid & 63;
    const int wave = tid >> 6;
    const int wr = wave >> 1, wc = wave & 1;   // 2x2 waves of 64x64
    const int lrow = lane & 15;
    const int kg   = lane >> 4;

    f32x4 acc[4][4] = {};

    auto stage = [&](int bb, int k0) {
#pragma unroll
        for (int i = 0; i < 2; ++i) {          // A tile: 512 x 16B chunks
            int chunk = i * 256 + tid;
            int r = chunk >> 2, cg = chunk & 3;
            const u16* ga = A + (long)(row0 + r) * lda + (k0 + cg * 8);
            u16* la = tA[bb] + (size_t)(i * 256 + wave * 64) * 8;  // wave-uniform
            __builtin_amdgcn_global_load_lds(
                (const __attribute__((address_space(1))) void*)ga,
                (__attribute__((address_space(3))) void*)la, 16, 0, 0);
        }
#pragma unroll
        for (int i = 0; i < 2; ++i) {          // B tile
            int chunk = i * 256 + tid;
            int r = chunk >> 2, cg = chunk & 3;
            const u16* gb = Bm + (long)(col0 + r) * ldb + (k0 + cg * 8);
            u16* lb = tB[bb] + (size_t)(i * 256 + wave * 64) * 8;
            __builtin_amdgcn_global_load_lds(
                (const __attribute__((address_space(1))) void*)gb,
                (__attribute__((address_space(3))) void*)lb, 16, 0, 0);
        }
    };

    stage(0, kBeg);
    int cur = 0;

    for (int k0 = kBeg; k0 < kEnd; k0 += 32) {
        __syncthreads();                 // buf[cur] staged (vmcnt drained);
                                         // prior reads of buf[cur^1] done
        if (k0 + 32 < kEnd) stage(cur ^ 1, k0 + 32);   // prefetch overlaps

        const u16* pA_ = tA[cur];
        const u16* pB_ = tB[cur];
        bf16x8 af[4], bfr[4];
#pragma unroll
        for (int ti = 0; ti < 4; ++ti)
            af[ti] = *(const bf16x8*)&pA_[(wr * 64 + ti * 16 + lrow) * 32 + kg * 8];
#pragma unroll
        for (int tj = 0; tj < 4; ++tj)
            bfr[tj] = *(const bf16x8*)&pB_[(wc * 64 + tj * 16 + lrow) * 32 + kg * 8];
#pragma unroll
        for (int ti = 0; ti < 4; ++ti)
#pragma unroll
            for (int tj = 0; tj < 4; ++tj)
                acc[ti][tj] = __builtin_amdgcn_mfma_f32_16x16x32_bf16(
                    af[ti], bfr[tj], acc[ti][tj], 0, 0, 0);
        cur ^= 1;
    }

    // Epilogue: D[row = kg*4 + r][col = lane&15] per 16x16 tile.
    const int rbase = row0 + wr * 64;
    const int cbase = col0 + wc * 64 + lrow;

    if (MODE == 0) {
        if (siluMode) {
            const bool even = ((lrow & 1) == 0);
            const int ccb = ((col0 + wc * 64) >> 1) + (lrow >> 1);
#pragma unroll
            for (int ti = 0; ti < 4; ++ti) {
#pragma unroll
                for (int r = 0; r < 4; ++r) {
                    int row = rbase + ti * 16 + kg * 4 + r;
#pragma unroll
                    for (int tj = 0; tj < 4; ++tj) {
                        float v = acc[ti][tj][r];
                        float pv = __shfl_xor(v, 1);
                        if (even) {
                            float res = (v / (1.f + __expf(-v))) * pv;
                            Cb[(long)row * ldc + ccb + tj * 8] = f2b(res);
                        }
                    }
                }
            }
        } else {
            const bool doRope = ropeMode && (cbase < 2048);  // q|k cols of qkv
#pragma unroll
            for (int ti = 0; ti < 4; ++ti) {
#pragma unroll
                for (int r = 0; r < 4; ++r) {
                    int row = rbase + ti * 16 + kg * 4 + r;
                    float o0 = acc[ti][0][r], o1 = acc[ti][1][r];
                    float o2 = acc[ti][2][r], o3 = acc[ti][3][r];
                    if (doRope) {
                        int t = row & 1023;
                        float2 c0 = rt[t * 32 + lrow];         // i = lrow
                        float2 c1 = rt[t * 32 + 16 + lrow];    // i = 16 + lrow
                        float n0 = o0 * c0.x - o2 * c0.y;
                        float n2 = o2 * c0.x + o0 * c0.y;
                        float n1 = o1 * c1.x - o3 * c1.y;
                        float n3 = o3 * c1.x + o1 * c1.y;
                        o0 = n0; o1 = n1; o2 = n2; o3 = n3;
                    }
                    float ov[4] = { o0, o1, o2, o3 };
#pragma unroll
                    for (int tj = 0; tj < 4; ++tj)
                        Cb[(long)row * ldc + cbase + tj * 16] = f2b(ov[tj]);
                }
            }
        }
    } else {
        const size_t pstr = (size_t)M * ldc;
        const bool last = (z == kSplit - 1);
#pragma unroll
        for (int ti = 0; ti < 4; ++ti) {
#pragma unroll
            for (int r = 0; r < 4; ++r) {
                int row = rbase + ti * 16 + kg * 4 + r;
#pragma unroll
                for (int tj = 0; tj < 4; ++tj) {
                    long off = (long)row * ldc + cbase + tj * 16;
                    if (last) Cf[off] += acc[ti][tj][r];   // single writer/cell
                    else      Pf[(size_t)z * pstr + off] = acc[ti][tj][r];
                }
            }
        }
    }
}

// ---------------------------------------------------------------------------
// Fused causal flash attention. One block = (b, head, 64 q-rows), 4 waves x
// 16 q-rows. K/V tiles double-buffered in LDS via global_load_lds with
// pre-swizzled global source; prefetch of tile j+1 overlaps compute of j.
// Longest q-tiles are dispatched first (qt = 15 - pos) to trim the tail.
// ---------------------------------------------------------------------------
__global__ __launch_bounds__(256, 2)
void flash_k(const u16* __restrict__ qkv, const u16* __restrict__ vt,
             u16* __restrict__ y)
{
    __shared__ __align__(16) u16 tK[2][64 * 64];
    __shared__ __align__(16) u16 tV[2][64 * 64];
    __shared__ __align__(16) u16 tP[4][16 * 64];

    const int bid0 = blockIdx.x;
    const int bid  = (bid0 & 7) * 64 + (bid0 >> 3);   // XCD swizzle (512%8==0)
    const int qt = 15 - (bid & 15);                   // longest first
    const int hh = (bid >> 4) & 15;
    const int b  = bid >> 8;

    const int tid  = threadIdx.x;
    const int lane = tid & 63;
    const int w    = tid >> 6;           // wave 0..3
    const int l15  = lane & 15;
    const int kg   = lane >> 4;          // 0..3

    const int wq0 = qt * 64 + w * 16;    // wave's first q row
    u16* tPw = tP[w];

    bf16x8 qf[2];
#pragma unroll
    for (int dk = 0; dk < 2; ++dk)
        qf[dk] = *(const bf16x8*)(qkv
            + (size_t)(b * 1024 + wq0 + l15) * 3072 + hh * 64 + dk * 32 + kg * 8);

    f32x4 acc_o[4] = {};
    float mrun = -3e38f;
    float lrun = 0.f;

    const u16* Kg0 = qkv + (size_t)(b * 1024) * 3072 + 1024 + hh * 64;
    const u16* Vg0 = vt + (size_t)((b * 16 + hh) * 64) * 1024;

    auto stage = [&](int bb, int j) {
#pragma unroll
        for (int i = 0; i < 2; ++i) {
            int chunk = i * 256 + tid;   // granule id 0..511
            int row = chunk >> 3, gc = chunk & 7;
            int sgc = gc ^ (row & 7);
            const u16* ga = Kg0 + (size_t)(j * 64 + row) * 3072 + sgc * 8;
            u16* la = tK[bb] + (size_t)(i * 256 + w * 64) * 8;  // wave-uniform
            __builtin_amdgcn_global_load_lds(
                (const __attribute__((address_space(1))) void*)ga,
                (__attribute__((address_space(3))) void*)la, 16, 0, 0);
            const u16* gb = Vg0 + (size_t)row * 1024 + j * 64 + sgc * 8;
            u16* lb = tV[bb] + (size_t)(i * 256 + w * 64) * 8;
            __builtin_amdgcn_global_load_lds(
                (const __attribute__((address_space(1))) void*)gb,
                (__attribute__((address_space(3))) void*)lb, 16, 0, 0);
        }
    };

    stage(0, 0);
    int cur = 0;

    for (int j = 0; j <= qt; ++j) {
        __syncthreads();
        if (j < qt) stage(cur ^ 1, j + 1);   // prefetch overlaps compute

        const u16* K_ = tK[cur];
        const u16* V_ = tV[cur];

        f32x4 s[4] = {};
#pragma unroll
        for (int dk = 0; dk < 2; ++dk) {
            bf16x8 ak[4];
#pragma unroll
            for (int kvt = 0; kvt < 4; ++kvt) {
                int row = kvt * 16 + l15;
                int g = (dk * 4 + kg) ^ (row & 7);
                ak[kvt] = *(const bf16x8*)&K_[row * 64 + g * 8];
            }
#pragma unroll
            for (int kvt = 0; kvt < 4; ++kvt)
                s[kvt] = __builtin_amdgcn_mfma_f32_16x16x32_bf16(
                    ak[kvt], qf[dk], s[kvt], 0, 0, 0);
        }

        float tmax = -3e38f;
        const bool maskt = (j == qt);
#pragma unroll
        for (int kvt = 0; kvt < 4; ++kvt) {
            f32x4 v = s[kvt];
#pragma unroll
            for (int r = 0; r < 4; ++r) {
                float sv = v[r] * 0.125f;
                if (maskt && (j * 64 + kvt * 16 + kg * 4 + r > wq0 + l15))
                    sv = -3e38f;
                v[r] = sv;
                tmax = fmaxf(tmax, sv);
            }
            s[kvt] = v;
        }
        tmax = fmaxf(tmax, __shfl_xor(tmax, 16));
        tmax = fmaxf(tmax, __shfl_xor(tmax, 32));

        const float mn = fmaxf(mrun, tmax);
        const float sf = __expf(mrun - mn);
        mrun = mn;

#pragma unroll
        for (int ro = 0; ro < 4; ++ro) {
            float f = __shfl(sf, kg * 4 + ro);
#pragma unroll
            for (int dj = 0; dj < 4; ++dj)
                acc_o[dj][ro] *= f;
        }

        float tsum = 0.f;
#pragma unroll
        for (int kvt = 0; kvt < 4; ++kvt) {
            f32x4 v = s[kvt];
            float p0 = __expf(v[0] - mn);
            float p1 = __expf(v[1] - mn);
            float p2 = __expf(v[2] - mn);
            float p3 = __expf(v[3] - mn);
            tsum += p0 + p1 + p2 + p3;
            ushort4 pk;
            pk.x = f2b(p0); pk.y = f2b(p1); pk.z = f2b(p2); pk.w = f2b(p3);
            int g = (kvt * 2 + (kg >> 1)) ^ (l15 & 7);
            *(ushort4*)&tPw[l15 * 64 + g * 8 + (kg & 1) * 4] = pk;
        }
        tsum += __shfl_xor(tsum, 16);
        tsum += __shfl_xor(tsum, 32);
        lrun = lrun * sf + tsum;

#pragma unroll
        for (int ki = 0; ki < 2; ++ki) {
            bf16x8 ap, bv[4];
            {
                int g = (ki * 4 + kg) ^ (l15 & 7);
                ap = *(const bf16x8*)&tPw[l15 * 64 + g * 8];
            }
#pragma unroll
            for (int dj = 0; dj < 4; ++dj) {
                int row = dj * 16 + l15;
                int g = (ki * 4 + kg) ^ (row & 7);
                bv[dj] = *(const bf16x8*)&V_[row * 64 + g * 8];
            }
#pragma unroll
            for (int dj = 0; dj < 4; ++dj)
                acc_o[dj] = __builtin_amdgcn_mfma_f32_16x16x32_bf16(
                    ap, bv[dj], acc_o[dj], 0, 0, 0);
        }
        cur ^= 1;
    }

    const float inv = 1.0f / lrun;
#pragma unroll
    for (int ro = 0; ro < 4; ++ro) {
        float iv = __shfl(inv, kg * 4 + ro);
        size_t rowo = (size_t)(b * 1024 + wq0 + kg * 4 + ro) * 1024
                    + hh * 64 + l15;
#pragma unroll
        for (int dj = 0; dj < 4; ++dj)
            y[rowo + dj * 16] = f2b(acc_o[dj][ro] * iv);
    }
}

// h[bt,c] = sum_f x[bt,f] * w_in[c,f]   (K=9, fp32 out)
__global__ void input_proj_k(const u16* __restrict__ x, const u16* __restrict__ w,
                             float* __restrict__ h)
{
    int idx = blockIdx.x * 256 + threadIdx.x;      // 2M
    int bt = idx >> 10, c = idx & 1023;
    float s = 0.f;
#pragma unroll
    for (int f = 0; f < 9; ++f) s += b2f(x[bt * 9 + f]) * b2f(w[c * 9 + f]);
    h[idx] = s;
}

// Fused residual-reduce + RMSNorm.
// v = h[row] + sum_{p<nP} P[p][row];  if (hOut) hOut[row] = v;
// out[row] = v * rsqrt(mean(v^2)+eps) * g.   isFinal&&flag -> fp32 out.
__global__ void rms_k(const float* __restrict__ h, const float* __restrict__ P,
                      int nP, const u16* __restrict__ g,
                      void* __restrict__ out, float* __restrict__ hOut,
                      int isFinal, const int* __restrict__ flag)
{
    __shared__ float red[8];
    const int row = blockIdx.x;
    const int tid = threadIdx.x;
    float4 v = ((const float4*)(h + (size_t)row * C_))[tid];
    for (int p = 0; p < nP; ++p) {
        float4 pv = ((const float4*)P)[(size_t)p * 524288 + row * 256 + tid];
        v.x += pv.x; v.y += pv.y; v.z += pv.z; v.w += pv.w;
    }
    if (hOut) ((float4*)hOut)[(size_t)row * 256 + tid] = v;
    float ss = v.x * v.x + v.y * v.y + v.z * v.z + v.w * v.w;
#pragma unroll
    for (int off = 32; off; off >>= 1) ss += __shfl_down(ss, off);
    int lane = tid & 63, wave = tid >> 6;
    if (lane == 0) red[wave] = ss;
    __syncthreads();
    if (tid == 0)
        red[4] = rsqrtf((red[0] + red[1] + red[2] + red[3]) / (float)C_ + EPS_);
    __syncthreads();
    const float r = red[4];
    ushort4 gv = ((const ushort4*)g)[tid];
    float o0 = v.x * r * b2f(gv.x);
    float o1 = v.y * r * b2f(gv.y);
    float o2 = v.z * r * b2f(gv.z);
    float o3 = v.w * r * b2f(gv.w);
    if (isFinal && flag[0]) {
        ((float4*)out)[(size_t)row * 256 + tid] = make_float4(o0, o1, o2, o3);
    } else {
        ushort4 o; o.x = f2b(o0); o.y = f2b(o1); o.z = f2b(o2); o.w = f2b(o3);
        ((ushort4*)out)[(size_t)row * 256 + tid] = o;
    }
}

// cos/sin table: tab[t*32+i] = {cos,sin}(t * 10000^(-i/32)), t<1024, i<32
__global__ void rope_tab_k(float2* __restrict__ tab)
{
    int idx = blockIdx.x * 256 + threadIdx.x;      // 32768
    int i = idx & 31;
    int t = idx >> 5;
    float invf = powf(10000.0f, -(float)i / 32.0f);
    float fr = (float)t * invf;
    tab[idx] = make_float2(cosf(fr), sinf(fr));
}

// vt[b,h,d,s] = qkv[b,s, 2048 + h*64 + d]  — LDS-tiled 64x64 transpose.
__global__ void vtrans_k(const u16* __restrict__ qkv, u16* __restrict__ vt)
{
    __shared__ u16 tile[64][68];                   // pad 4 u16
    const int bz = blockIdx.x;                     // 512 = 2b * 16h * 16s-tiles
    const int s0 = (bz & 15) << 6;
    const int hh = (bz >> 4) & 15;
    const int b  = bz >> 8;
    const int tid = threadIdx.x;
#pragma unroll
    for (int it = 0; it < 2; ++it) {
        int id = it * 256 + tid;                   // 0..511
        int r  = id >> 3;                          // s-row within tile
        int cg = id & 7;                           // 8-wide d chunk
        const u16* src = qkv + (size_t)(b * 1024 + s0 + r) * 3072
                             + 2048 + hh * 64 + cg * 8;
        ushort4 a0 = *(const ushort4*)src;
        ushort4 a1 = *(const ushort4*)(src + 4);
        *(ushort4*)&tile[r][cg * 8]     = a0;
        *(ushort4*)&tile[r][cg * 8 + 4] = a1;
    }
    __syncthreads();
#pragma unroll
    for (int it = 0; it < 2; ++it) {
        int id = it * 256 + tid;
        int d  = id >> 3;                          // d row of output
        int cg = id & 7;                           // 8-wide s chunk
        ushort4 o0, o1;
        o0.x = tile[cg * 8 + 0][d]; o0.y = tile[cg * 8 + 1][d];
        o0.z = tile[cg * 8 + 2][d]; o0.w = tile[cg * 8 + 3][d];
        o1.x = tile[cg * 8 + 4][d]; o1.y = tile[cg * 8 + 5][d];
        o1.z = tile[cg * 8 + 6][d]; o1.w = tile[cg * 8 + 7][d];
        u16* dst = vt + (size_t)((b * 16 + hh) * 64 + d) * 1024 + s0 + cg * 8;
        *(ushort4*)dst       = o0;
        *(ushort4*)(dst + 4) = o1;
    }
}

// ---------------------------------------------------------------------------
static inline void launch_gemm(bool add, const u16* A, const u16* Bm, void* C,
                               float* Pf,
                               int M, int N, int K, int lda, int ldb, int ldc,
                               int kSplit, int ropeMode, int siluMode,
                               const float2* rt, hipStream_t stream)
{
    dim3 g(N / 128, M / 128, add ? kSplit : 1);
    if (add)
        gemm_bt<1><<<g, 256, 0, stream>>>(A, Bm, nullptr, (float*)C, Pf,
            M, N, K, lda, ldb, ldc, kSplit, 0, 0, nullptr);
    else
        gemm_bt<0><<<g, 256, 0, stream>>>(A, Bm, (u16*)C, nullptr, nullptr,
            M, N, K, lda, ldb, ldc, 1, ropeMode, siluMode, rt);
}

extern "C" void kernel_launch(void* const* d_in, const int* in_sizes, int n_in,
                              void* d_out, int out_size, void* d_ws, size_t ws_size,
                              hipStream_t stream)
{
    char* w = (char*)d_ws;
    // Layout:
    //   [0,8)    h fp32 residual
    //   [8,32)   P: 3 fp32 split-K partial slices (8 MB each); overlaps
    //            qkv [12,24) and vt [24,28) (disjoint lifetimes)
    //   [32,44)  u1c MLP compact buffer [2048][2816] bf16 (11.5 MB)
    //   [56,60)  y attention output
    //   [60,64)  a (rms output, bf16)
    float* h   = (float*)w;
    float* P   = (float*)(w + (8u  << 20));
    u16* qkv   = (u16*)(w + (12u << 20));
    u16* vt    = (u16*)(w + (24u << 20));
    u16* u1c   = (u16*)(w + (32u << 20));
    u16* y     = (u16*)(w + (56u << 20));
    u16* a     = (u16*)(w + (60u << 20));

    size_t off = (size_t)64 << 20;
    u16* cx    = (u16*)(w + off); off += ((size_t)B_*T_*9*2   + 255) & ~(size_t)255;
    u16* cwin  = (u16*)(w + off); off += ((size_t)C_*9*2      + 255) & ~(size_t)255;
    u16* cwqkv = (u16*)(w + off); off += (size_t)L_*3072*1024*2;   // fused q|k|v
    u16* cwo   = (u16*)(w + off); off += (size_t)L_*C_*C_*2;
    u16* cw12  = (u16*)(w + off); off += (size_t)L_*2*HFF_*C_*2;   // interleaved
    u16* cw3   = (u16*)(w + off); off += (size_t)L_*C_*HFF_*2;
    u16* cg1   = (u16*)(w + off); off += ((size_t)L_*C_*2 + 255) & ~(size_t)255;
    u16* cg2   = (u16*)(w + off); off += ((size_t)L_*C_*2 + 255) & ~(size_t)255;
    u16* cgf   = (u16*)(w + off); off += ((size_t)C_*2    + 255) & ~(size_t)255;
    int* flag  = (int*)(w + off); off += 256;
    float2* rtab = (float2*)(w + off);               // 1024*32*8 = 256 KB

    detect_k<<<1, 64, 0, stream>>>((const unsigned int*)d_in[0], flag);

    // --- fused weight conversion: one descriptor per (tensor, layer) ---
    const long CCv  = (long)C_ * C_ / 4;        // 262144
    const long HCv  = (long)HFF_ * C_ / 4;      // 720896
    CvtPack cp;
    int nd = 0;
    auto add = [&](const void* s, u16* d, long srcOff, long n, int mode) {
        cp.d[nd] = { s, d, srcOff, n, mode, 0 };
        ++nd;
    };
    add(d_in[0], cx,   0, (long)B_*T_*9/4, 0);
    add(d_in[1], cwin, 0, (long)C_*9/4,    0);
    for (int l = 0; l < L_; ++l)   // wq -> cwqkv cols 0..1023 row-block
        add(d_in[2], cwqkv + (size_t)l*3*CCv*4,           (long)l*CCv,   CCv,   0);
    for (int l = 0; l < L_; ++l)   // wkv
        add(d_in[3], cwqkv + (size_t)(l*3*CCv + CCv)*4,   (long)l*2*CCv, 2*CCv, 0);
    for (int l = 0; l < L_; ++l)   // wo
        add(d_in[4], cwo + (size_t)l*CCv*4,               (long)l*CCv,   CCv,   0);
    for (int l = 0; l < L_; ++l)   // w1 -> even rows of interleaved cw12
        add(d_in[5], cw12 + (size_t)l*2*HCv*4,            (long)l*HCv,   HCv,   1);
    for (int l = 0; l < L_; ++l)   // w2 -> odd rows
        add(d_in[6], cw12 + (size_t)l*2*HCv*4,            (long)l*HCv,   HCv,   2);
    for (int l = 0; l < L_; ++l)   // w3
        add(d_in[7], cw3 + (size_t)l*HCv*4,               (long)l*HCv,   HCv,   0);
    add(d_in[8],  cg1, 0, (long)L_*C_/4, 0);
    add(d_in[9],  cg2, 0, (long)L_*C_/4, 0);
    add(d_in[10], cgf, 0, (long)C_/4,    0);
    // nd == 29
    cvt_all_k<<<dim3(160, 29), 256, 0, stream>>>(cp, flag);

    rope_tab_k<<<128, 256, 0, stream>>>(rtab);

    input_proj_k<<<8192, 256, 0, stream>>>(cx, cwin, h);

    for (int l = 0; l < L_; ++l) {
        const u16* wqkv_l = cwqkv + (size_t)l * 3072 * 1024;
        const u16* wo_l   = cwo   + (size_t)l * C_ * C_;
        const u16* w12_l  = cw12  + (size_t)l * 2 * HFF_ * C_;
        const u16* w3_l   = cw3   + (size_t)l * C_ * HFF_;

        // --- attention ---
        if (l == 0)
            rms_k<<<2048, 256, 0, stream>>>(h, nullptr, 0, cg1, a, nullptr, 0, flag);
        else
            rms_k<<<2048, 256, 0, stream>>>(h, P, 3, cg1 + l * C_, a, h, 0, flag);
        // qkv[2048][3072] = a @ [wq|wk|wv]^T  (single N=3072 GEMM; RoPE fused)
        launch_gemm(false, a, wqkv_l, qkv, nullptr,
                    2048, 3072, 1024, 1024, 1024, 3072, 1, 1, 0, rtab, stream);
        vtrans_k<<<512, 256, 0, stream>>>(qkv, vt);
        flash_k<<<512, 256, 0, stream>>>(qkv, vt, y);
        // wo split-K x4: slices 0-2 -> P, slice 3 RMW h += acc
        launch_gemm(true, y, wo_l, h, P, 2048, 1024, 1024, 1024, 1024, 1024,
                    4, 0, 0, nullptr, stream);

        // --- MLP ---
        rms_k<<<2048, 256, 0, stream>>>(h, P, 3, cg2 + l * C_, a, h, 0, flag);
        // u1c[2048][2816] = silu(a@w1^T) * (a@w2^T) — interleaved B + fused silu
        launch_gemm(false, a, w12_l, u1c, nullptr,
                    2048, 5632, 1024, 1024, 1024, 2816, 1, 0, 1, nullptr, stream);
        // w3 split-K x4 (K=2816 -> 704/slice): slices 0-2 -> P, slice 3 RMW h
        launch_gemm(true, u1c, w3_l, h, P, 2048, 1024, 2816, 2816, 2816, 1024,
                    4, 0, 0, nullptr, stream);
    }

    rms_k<<<2048, 256, 0, stream>>>(h, P, 3, cgf, d_out, nullptr, 1, flag);
}